// Round 8
// baseline (94.773 us; speedup 1.0000x reference)
//
#include <hip/hip_runtime.h>
#include <math.h>

// TripletLoss N=8192, D=128, labels in [0,512). Round 11 = round 10 resubmit
// (round-10 bench died to a container-acquisition flake, same as round 3;
//  kernel re-audited: pin is a zero-inst liveness anchor, swizzle bijective).
//   Diagnosis: pair VGPR_Count=64 across rounds despite ~110 live demand
//   => compiler REMATERIALIZES bfrag (reloads i-side frags from global
//   inside the j-loop). Hidden VMEM latency per tile explains the ~14%
//   MfmaUtil plateau and why all scheduling knobs were neutral.
//   Fix: asm "+v" anchors force bfrag residency (launch_bounds(256,4)
//   budget 128 >= demand ~110). Plus XCD-aware block swizzle (each XCD
//   gets 4 contiguous j-chunks -> 32x L2 reuse of staged j-data).
//   memset(4KB) + prep + pair + reduce, as round 9 otherwise.
// Self-pair never wins hp (u_self=+0.5*sq_i is max-u; hp takes min-u);
// validity = hist[lab]>=2 && hist[lab]<N, matching the reference mask.
// Note: harness poisons the 256MB workspace (~42us fillBuffer) inside the
// timed window every iteration — a floor we don't control.

#define NROWS 8192
#define DIM   128
#define JSPLIT 32
#define JCHUNK (NROWS / JSPLIT)   // 256 j per y-block
#define NSUB   4                  // 64-row subtiles per j-chunk
#define SUBROWS 64

typedef short bf16x8 __attribute__((ext_vector_type(8)));
typedef float f32x4  __attribute__((ext_vector_type(4)));

static __device__ __forceinline__ unsigned short f2bf(float f) {
    unsigned u = __float_as_uint(f);
    unsigned r = (u + 0x7FFFu + ((u >> 16) & 1u)) >> 16;   // RNE
    return (unsigned short)r;
}

// order-preserving float<->uint encoding: unsigned compare == float compare
static __device__ __forceinline__ unsigned encf(float f) {
    unsigned u = __float_as_uint(f);
    return (u & 0x80000000u) ? ~u : (u | 0x80000000u);
}
static __device__ __forceinline__ float decf(unsigned e) {
    unsigned u = (e & 0x80000000u) ? (e & 0x7FFFFFFFu) : ~e;
    return __uint_as_float(u);
}
#define ENC_PINF 0xFF800000u   // encf(+INF) — init for min
#define ENC_NINF 0x007FFFFFu   // encf(-INF) — init for max

static __device__ __forceinline__ void gload_lds16(const void* g, void* l) {
    __builtin_amdgcn_global_load_lds(
        (const __attribute__((address_space(1))) unsigned int*)g,
        (__attribute__((address_space(3))) unsigned int*)l, 16, 0, 0);
}

// ---------------- K1: prep — sq, bf16, hist, minmax init ----------------
__global__ __launch_bounds__(256) void prep_kernel(
    const float* __restrict__ x, const int* __restrict__ labels,
    int* __restrict__ hist, float* __restrict__ sqp,
    float* __restrict__ sqh, unsigned* __restrict__ hpE,
    unsigned* __restrict__ hnE, unsigned short* __restrict__ xb) {
    int t = blockIdx.x * 256 + threadIdx.x;
    int row = t >> 5;
    int c = t & 31;
    float4 v = ((const float4*)x)[t];
    float ps = v.x * v.x + v.y * v.y + v.z * v.z + v.w * v.w;
#pragma unroll
    for (int s = 1; s < 32; s <<= 1) ps += __shfl_xor(ps, s, 64);
    if (c == 0) {
        sqp[row] = ps;
        sqh[row] = -0.5f * ps;
        atomicAdd(&hist[labels[row]], 1);
    } else if (c == 1) {
        hpE[row] = ENC_PINF;
    } else if (c == 2) {
        hnE[row] = ENC_NINF;
    }
    ushort4 ob;
    ob.x = f2bf(v.x); ob.y = f2bf(v.y); ob.z = f2bf(v.z); ob.w = f2bf(v.w);
    ((ushort4*)xb)[t] = ob;
}

// ---------------- K2: pair kernel (pinned bfrag, XCD swizzle) ------------
__global__ __launch_bounds__(256, 4) void pair_kernel(
    const unsigned short* __restrict__ xb, const float* __restrict__ sqh,
    const int* __restrict__ labels,
    unsigned* __restrict__ hpE, unsigned* __restrict__ hnE) {
    __shared__ __attribute__((aligned(16))) unsigned char abuf[2][SUBROWS * 256];
    __shared__ __attribute__((aligned(16))) float sqs[JCHUNK];
    __shared__ __attribute__((aligned(16))) int labs[JCHUNK];

    const int tid = threadIdx.x;
    const int lane = tid & 63;
    const int wid = tid >> 6;        // 0..3
    const int q = lane >> 4;         // 0..3
    const int r = lane & 15;

    // XCD-aware swizzle: 1024 blocks, XCD k gets wg in [k*128,(k+1)*128)
    // = j-chunks [k*4, k*4+4) — 32x L2 reuse of each staged j-chunk.
    const int bid = blockIdx.x;
    const int wg = (bid & 7) * 128 + (bid >> 3);
    const int ibase = (wg & 31) * 256 + wid * 64;
    const int jbase = (wg >> 5) * JCHUNK;

    sqs[tid] = sqh[jbase + tid];     // -0.5*sq_j
    labs[tid] = labels[jbase + tid];

    // B-frags (i side), resident for the whole j-loop.
    bf16x8 bfrag[4][4];
    int labi[4];
#pragma unroll
    for (int sub = 0; sub < 4; ++sub) {
        int irow = ibase + sub * 16 + r;
        labi[sub] = labels[irow];
#pragma unroll
        for (int ks = 0; ks < 4; ++ks)
            bfrag[sub][ks] = *(const bf16x8*)(xb + (size_t)irow * DIM + ks * 32 + q * 8);
    }
    // Pin the fragments: "+v" marks them redefined, so the compiler cannot
    // rematerialize (re-load) them inside the j-loop. This is the fix for
    // the VGPR_Count=64 remat plateau (demand ~110, budget 128).
#pragma unroll
    for (int sub = 0; sub < 4; ++sub)
#pragma unroll
        for (int ks = 0; ks < 4; ++ks)
            asm volatile("" : "+v"(bfrag[sub][ks]));

    float hp[4] = {INFINITY, INFINITY, INFINITY, INFINITY};     // min u (pos)
    float hn[4] = {-INFINITY, -INFINITY, -INFINITY, -INFINITY}; // max u (neg)

    // Stage subtile s (64 rows x 128 bf16 = 16 KB), swizzled source
    // (rule 21): LDS[row][c] = G[row][c ^ ((row&15)<<4)], linear dest.
    auto stage = [&](int s, int buf) {
        const char* gb = (const char*)xb + (size_t)(jbase + s * SUBROWS) * 256;
        unsigned char* lb = &abuf[buf][0];
#pragma unroll
        for (int p = 0; p < 4; ++p) {
            int row = wid * 16 + p * 4 + (lane >> 4);
            int colb = (lane & 15) * 16;
            const void* g = gb + row * 256 + (colb ^ ((row & 15) << 4));
            void* l = lb + wid * 4096 + p * 1024;   // wave-uniform base
            gload_lds16(g, l);
        }
    };

    auto compute_tile = [&](int s, int buf, int t) {
        const unsigned char* lb = &abuf[buf][0];
        const int tt = s * 4 + t;    // 16-row tile index within chunk, 0..15
        bf16x8 af[4];
        const int rowb = (t * 16 + r) * 256;
        const int sw = r << 4;       // (row&15)<<4, row = t*16+r
#pragma unroll
        for (int ks = 0; ks < 4; ++ks)
            af[ks] = *(const bf16x8*)(lb + rowb + ((ks * 64 + q * 16) ^ sw));
        f32x4 ci = *(const f32x4*)(&sqs[tt * 16 + q * 4]);
        int4 labj = *(const int4*)(labs + tt * 16 + q * 4);
#pragma unroll
        for (int sub = 0; sub < 4; ++sub) {
            f32x4 acc = ci;
            acc = __builtin_amdgcn_mfma_f32_16x16x32_bf16(af[0], bfrag[sub][0], acc, 0, 0, 0);
            acc = __builtin_amdgcn_mfma_f32_16x16x32_bf16(af[1], bfrag[sub][1], acc, 0, 0, 0);
            acc = __builtin_amdgcn_mfma_f32_16x16x32_bf16(af[2], bfrag[sub][2], acc, 0, 0, 0);
            acc = __builtin_amdgcn_mfma_f32_16x16x32_bf16(af[3], bfrag[sub][3], acc, 0, 0, 0);
            const int li = labi[sub];
            float u0 = acc[0], u1 = acc[1], u2 = acc[2], u3 = acc[3];
            hp[sub] = fminf(hp[sub], (labj.x == li) ? u0 : INFINITY);
            hn[sub] = fmaxf(hn[sub], (labj.x == li) ? -INFINITY : u0);
            hp[sub] = fminf(hp[sub], (labj.y == li) ? u1 : INFINITY);
            hn[sub] = fmaxf(hn[sub], (labj.y == li) ? -INFINITY : u1);
            hp[sub] = fminf(hp[sub], (labj.z == li) ? u2 : INFINITY);
            hn[sub] = fmaxf(hn[sub], (labj.z == li) ? -INFINITY : u2);
            hp[sub] = fminf(hp[sub], (labj.w == li) ? u3 : INFINITY);
            hn[sub] = fmaxf(hn[sub], (labj.w == li) ? -INFINITY : u3);
        }
    };

    // m97 two-barrier pipeline: stage(s+1) in flight while computing s.
    stage(0, 0);
    __syncthreads();
#pragma unroll
    for (int s = 0; s < NSUB; ++s) {
        if (s + 1 < NSUB) stage(s + 1, (s + 1) & 1);
#pragma unroll
        for (int t = 0; t < 4; ++t) compute_tile(s, s & 1, t);
        __syncthreads();
    }

    // reduce across the 4 q-groups (lanes r, r+16, r+32, r+48)
#pragma unroll
    for (int sub = 0; sub < 4; ++sub) {
        hp[sub] = fminf(hp[sub], __shfl_xor(hp[sub], 16, 64));
        hp[sub] = fminf(hp[sub], __shfl_xor(hp[sub], 32, 64));
        hn[sub] = fmaxf(hn[sub], __shfl_xor(hn[sub], 16, 64));
        hn[sub] = fmaxf(hn[sub], __shfl_xor(hn[sub], 32, 64));
    }
    if (lane < 16) {
#pragma unroll
        for (int sub = 0; sub < 4; ++sub) {
            int irow = ibase + sub * 16 + lane;
            atomicMin(&hpE[irow], encf(hp[sub]));
            atomicMax(&hnE[irow], encf(hn[sub]));
        }
    }
}

// ---------------- K3: reduce + fused final ------------------------------
__global__ __launch_bounds__(256) void reduce_kernel(
    const unsigned* __restrict__ hpE, const unsigned* __restrict__ hnE,
    const float* __restrict__ sqp, const int* __restrict__ labels,
    const int* __restrict__ hist, float* __restrict__ gsum,
    float* __restrict__ gcnt, unsigned* __restrict__ done,
    float* __restrict__ out) {
    int row = blockIdx.x * 256 + threadIdx.x;
    float mnp = decf(hpE[row]);
    float mxn = decf(hnE[row]);
    float s = sqp[row];
    int h = hist[labels[row]];
    float sum = 0.f, cnt = 0.f;
    if (h >= 2 && h < NROWS) {
        float dp = sqrtf(fmaxf(s - 2.f * mnp, 1e-12f));
        float dn = sqrtf(fmaxf(s - 2.f * mxn, 1e-12f));
        sum = fmaxf(dp - dn + 0.3f, 1e-6f);
        cnt = 1.f;
    }
#pragma unroll
    for (int sh = 1; sh < 64; sh <<= 1) {
        sum += __shfl_xor(sum, sh, 64);
        cnt += __shfl_xor(cnt, sh, 64);
    }
    __shared__ float ss[4], sc[4];
    int w = threadIdx.x >> 6;
    if ((threadIdx.x & 63) == 0) { ss[w] = sum; sc[w] = cnt; }
    __syncthreads();
    if (threadIdx.x == 0) {
        atomicAdd(gsum, ss[0] + ss[1] + ss[2] + ss[3]);
        atomicAdd(gcnt, sc[0] + sc[1] + sc[2] + sc[3]);
        __threadfence();
        unsigned t = atomicAdd(done, 1u);
        if (t == gridDim.x - 1) {
            float S = atomicAdd(gsum, 0.f);   // coherent read via RMW
            float C = atomicAdd(gcnt, 0.f);
            out[0] = (C > 0.f) ? S / C : 0.f;
        }
    }
}

extern "C" void kernel_launch(void* const* d_in, const int* in_sizes, int n_in,
                              void* d_out, int out_size, void* d_ws, size_t ws_size,
                              hipStream_t stream) {
    const float* x = (const float*)d_in[0];
    const int* labels = (const int*)d_in[1];
    float* out = (float*)d_out;

    // ws layout:
    //   hist @ 0      (2 KB)  \
    //   gsum @ 2048, gcnt @ 2052, done @ 2056   } zeroed by one 4KB memset
    //   sqp  @ 4096   (32 KB)
    //   sqh  @ 36864  (32 KB)   -0.5*sq (pair cinit)
    //   hpE  @ 69632  (32 KB)   encoded min-u (positives)
    //   hnE  @ 102400 (32 KB)   encoded max-u (negatives)
    //   xb   @ 135168 (2 MB bf16)      total ~2.2 MB
    char* ws = (char*)d_ws;
    int* hist = (int*)ws;
    float* gsum = (float*)(ws + 2048);
    float* gcnt = (float*)(ws + 2052);
    unsigned* done = (unsigned*)(ws + 2056);
    float* sqp = (float*)(ws + 4096);
    float* sqh = (float*)(ws + 36864);
    unsigned* hpE = (unsigned*)(ws + 69632);
    unsigned* hnE = (unsigned*)(ws + 102400);
    unsigned short* xb = (unsigned short*)(ws + 135168);

    hipMemsetAsync(ws, 0, 4096, stream);
    prep_kernel<<<(NROWS * 32) / 256, 256, 0, stream>>>(
        x, labels, hist, sqp, sqh, hpE, hnE, xb);
    pair_kernel<<<1024, 256, 0, stream>>>(
        xb, sqh, labels, hpE, hnE);
    reduce_kernel<<<NROWS / 256, 256, 0, stream>>>(
        hpE, hnE, sqp, labels, hist, gsum, gcnt, done, out);
}